// Round 11
// baseline (222.668 us; speedup 1.0000x reference)
//
#include <hip/hip_runtime.h>
#include <hip/hip_bf16.h>

typedef unsigned short u16;
typedef unsigned int u32;
typedef __attribute__((ext_vector_type(8))) short bf16x8;
typedef __attribute__((ext_vector_type(4))) float f32x4;

#define S_LEN 4096
#define DHEAD 128
#define NHEAD 8
#define NBATCH 2

__device__ __forceinline__ u16 f2b(float f) {
  __hip_bfloat16 h = __float2bfloat16(f);
  return *(u16*)&h;
}

__device__ __forceinline__ f32x4 mfma16(bf16x8 a, bf16x8 b, f32x4 c) {
  return __builtin_amdgcn_mfma_f32_16x16x32_bf16(a, b, c, 0, 0, 0);
}

__device__ __forceinline__ f32x4 zero4() { f32x4 z = {0.f, 0.f, 0.f, 0.f}; return z; }

// async global->LDS, 16B per lane; LDS dest = wave-uniform base + lane*16
__device__ __forceinline__ void gll16(const u16* g, u16* l) {
  __builtin_amdgcn_global_load_lds(
      (const __attribute__((address_space(1))) u32*)g,
      (__attribute__((address_space(3))) u32*)l, 16, 0, 0);
}

// ---------------- converts ----------------
__global__ void k_conv_x(const float* __restrict__ x, u16* __restrict__ xb,
                         u16* __restrict__ xT) {
  int idx = blockIdx.x * blockDim.x + threadIdx.x;
  float v = x[idx];
  u16 bv = f2b(v);
  xb[idx] = bv;
  int d = idx & 127;
  int bs = idx >> 7;
  int b = bs >> 12;
  int s = bs & 4095;
  xT[((size_t)b * DHEAD + d) * S_LEN + s] = bv;
}

__global__ void k_conv_w(const float* __restrict__ Wq, const float* __restrict__ Wk,
                         const float* __restrict__ Wo, u16* __restrict__ Wqt,
                         u16* __restrict__ Wkt, u16* __restrict__ WoB) {
  int idx = blockIdx.x * blockDim.x + threadIdx.x;
  int h = idx >> 14;
  int d = (idx >> 7) & 127;
  int e = idx & 127;
  int t = (h << 14) + (e << 7) + d;
  Wqt[t] = f2b(Wq[idx]);
  Wkt[t] = f2b(Wk[idx]);
  WoB[idx] = f2b(Wo[idx]);
}

// ---------------- Q/K projection: 4 waves/block ----------------
__global__ __launch_bounds__(256) void k_proj(const u16* __restrict__ xb,
                                              const u16* __restrict__ Wqt,
                                              const u16* __restrict__ Wkt,
                                              u16* __restrict__ Qb, u16* __restrict__ Kb) {
  int wid = threadIdx.x >> 6;
  int lane = threadIdx.x & 63;
  int qt = blockIdx.x * 4 + wid;
  int h = blockIdx.y, z = blockIdx.z;
  int b = z >> 1, w = z & 1;
  int row16 = lane & 15, kgrp = lane >> 4;
  int sb = qt * 32;
  const u16* xp = xb + ((size_t)b * S_LEN + sb) * DHEAD;
  bf16x8 a[2][4];
#pragma unroll
  for (int r = 0; r < 2; ++r)
#pragma unroll
    for (int kc = 0; kc < 4; ++kc)
      a[r][kc] = *(const bf16x8*)(xp + (r * 16 + row16) * DHEAD + kc * 32 + kgrp * 8);

  const u16* Wt = (w == 0 ? Wqt : Wkt) + (size_t)h * DHEAD * DHEAD;
  u16* Out = (w == 0 ? Qb : Kb) + ((size_t)(b * NHEAD + h) * S_LEN + sb) * DHEAD;
  f32x4 acc[2][8];
#pragma unroll
  for (int r = 0; r < 2; ++r)
#pragma unroll
    for (int nc = 0; nc < 8; ++nc) acc[r][nc] = zero4();
#pragma unroll
  for (int kc = 0; kc < 4; ++kc)
#pragma unroll
    for (int nc = 0; nc < 8; ++nc) {
      bf16x8 bw = *(const bf16x8*)(Wt + (nc * 16 + row16) * DHEAD + kc * 32 + kgrp * 8);
      acc[0][nc] = mfma16(a[0][kc], bw, acc[0][nc]);
      acc[1][nc] = mfma16(a[1][kc], bw, acc[1][nc]);
    }
#pragma unroll
  for (int r = 0; r < 2; ++r)
#pragma unroll
    for (int nc = 0; nc < 8; ++nc)
#pragma unroll
      for (int i = 0; i < 4; ++i)
        Out[(size_t)(r * 16 + kgrp * 4 + i) * DHEAD + nc * 16 + row16] =
            f2b(acc[r][nc][i]);
}

// ---------------- causal flash attention: balanced qblk-pairs + gll ----------
// Block = (b,h, qblk-pair {j, 31-j}) -> EXACTLY 68 key-tiles per block.
// 256 blocks, 1/CU (LDS 82KB), flat concurrency: no causal tail.
// K/V staged via global_load_lds into fragment-linear LDS (conflict-free b128).
__global__ __launch_bounds__(256) void k_attn(const u16* __restrict__ Qb,
                                              const u16* __restrict__ Kb,
                                              const u16* __restrict__ xT,
                                              u16* __restrict__ Yb) {
  int p = blockIdx.x;                      // 0..255
  int xcd = p & 7;
  int j2 = p >> 3;                         // 0..31
  int bh = xcd + (j2 >= 16 ? 8 : 0);       // 0..15 (same (b,h) per XCD)
  int qpj = j2 & 15;
  int b = bh >> 3, h = bh & 7;

  int tid = threadIdx.x;
  int wid = tid >> 6;
  int lane = tid & 63;
  int row16 = lane & 15, kgrp = lane >> 4;

  const u16* Kp = Kb + (size_t)(b * NHEAD + h) * S_LEN * DHEAD;
  const u16* Vt = xT + (size_t)b * DHEAD * S_LEN;

  // fragment-linear: frag f at [f*512 .. f*512+512) u16; +pad to force 1 block/CU
  __shared__ __align__(16) u16 Klds[2][9216];       // 36 KB
  __shared__ __align__(16) u16 Vlds[2][9216];       // 36 KB
  __shared__ __align__(16) u16 plds[4][32][40];     // 10 KB

  // stage one 64-key tile: 16 K-frags + 16 V-frags, 4 gll each per wave
  auto issue = [&](int k0, int buf) {
#pragma unroll
    for (int fi = 0; fi < 4; ++fi) {
      int f = wid * 4 + fi;
      int kk = (f >> 3) & 1, nk = (f >> 2) & 1, kc = f & 3;
      const u16* src =
          Kp + (size_t)(k0 + kk * 32 + nk * 16 + row16) * DHEAD + kc * 32 + kgrp * 8;
      gll16(src, &Klds[buf][f * 512]);
    }
#pragma unroll
    for (int gi = 0; gi < 4; ++gi) {
      int g = wid * 4 + gi;
      int kk = g >> 3, nc = g & 7;
      const u16* src = Vt + (size_t)(nc * 16 + row16) * S_LEN + k0 + kk * 32 + kgrp * 8;
      gll16(src, &Vlds[buf][g * 512]);
    }
  };

  const float c2 = 0.12754274816295166f;    // (1/sqrt(128)) * log2(e)
  const float clip2 = 14.426950408889634f;  // 10 * log2(e)

  auto runSeg = [&](int qblk) {
    int qb0 = qblk * 128;
    int qw = qb0 + wid * 32;               // this wave's 32 q-rows
    const u16* Qp = Qb + ((size_t)(b * NHEAD + h) * S_LEN + qw) * DHEAD;

    bf16x8 aq[2][4];
#pragma unroll
    for (int r = 0; r < 2; ++r)
#pragma unroll
      for (int kc = 0; kc < 4; ++kc)
        aq[r][kc] = *(const bf16x8*)(Qp + (r * 16 + row16) * DHEAD + kc * 32 + kgrp * 8);

    f32x4 y[2][8];
#pragma unroll
    for (int r = 0; r < 2; ++r)
#pragma unroll
      for (int nc = 0; nc < 8; ++nc) y[r][nc] = zero4();
    f32x4 rs[2];
    rs[0] = zero4();
    rs[1] = zero4();

    auto subtile = [&](int buf, int k0, int kk) {
      bf16x8 kf[8];
#pragma unroll
      for (int nk = 0; nk < 2; ++nk)
#pragma unroll
        for (int kc = 0; kc < 4; ++kc)
          kf[nk * 4 + kc] =
              *(const bf16x8*)&Klds[buf][((kk * 8 + nk * 4 + kc) * 64 + lane) * 8];
      f32x4 sc[2][2];
      sc[0][0] = zero4(); sc[0][1] = zero4(); sc[1][0] = zero4(); sc[1][1] = zero4();
#pragma unroll
      for (int nk = 0; nk < 2; ++nk)
#pragma unroll
        for (int kcc = 0; kcc < 4; ++kcc) {
          sc[0][nk] = mfma16(aq[0][kcc], kf[nk * 4 + kcc], sc[0][nk]);
          sc[1][nk] = mfma16(aq[1][kcc], kf[nk * 4 + kcc], sc[1][nk]);
        }
#pragma unroll
      for (int r = 0; r < 2; ++r)
#pragma unroll
        for (int nk = 0; nk < 2; ++nk) {
          int key = k0 + kk * 32 + nk * 16 + row16;
#pragma unroll
          for (int i = 0; i < 4; ++i) {
            float v = sc[r][nk][i] * c2;
            v = fminf(fmaxf(v, -clip2), clip2);
            float pcur = __builtin_amdgcn_exp2f(v);
            int qrow = qw + r * 16 + kgrp * 4 + i;
            pcur = (key > qrow) ? 0.0f : pcur;   // branchless causal mask
            rs[r][i] += pcur;
            plds[wid][r * 16 + kgrp * 4 + i][nk * 16 + row16] = f2b(pcur);
          }
        }
      bf16x8 ap0 = *(const bf16x8*)&plds[wid][row16][kgrp * 8];
      bf16x8 ap1 = *(const bf16x8*)&plds[wid][16 + row16][kgrp * 8];
#pragma unroll
      for (int nc = 0; nc < 8; ++nc) {
        bf16x8 vf = *(const bf16x8*)&Vlds[buf][((kk * 8 + nc) * 64 + lane) * 8];
        y[0][nc] = mfma16(ap0, vf, y[0][nc]);
        y[1][nc] = mfma16(ap1, vf, y[1][nc]);
      }
    };

    int NT = 2 * qblk + 2;   // 64-key tiles covering keys 0..qb0+127
    issue(0, 0);
    __syncthreads();
    for (int t = 0; t < NT; ++t) {
      int k0 = t * 64;
      int cur = t & 1;
      if (t + 1 < NT) issue(k0 + 64, cur ^ 1);  // prefetch under full tile compute
      subtile(cur, k0, 0);
      subtile(cur, k0, 1);
      __syncthreads();  // drains vmcnt (prefetch landed) + LDS reads done
    }

    // reduce rs over the 16 row16 lanes of each kgrp group
#pragma unroll
    for (int r = 0; r < 2; ++r)
#pragma unroll
      for (int i = 0; i < 4; ++i) {
        float v = rs[r][i];
        v += __shfl_xor(v, 1, 64);
        v += __shfl_xor(v, 2, 64);
        v += __shfl_xor(v, 4, 64);
        v += __shfl_xor(v, 8, 64);
        rs[r][i] = v;
      }

    u16* Yp = Yb + ((size_t)b * S_LEN + qw) * (NHEAD * DHEAD) + h * DHEAD;
#pragma unroll
    for (int r = 0; r < 2; ++r) {
      float inv[4];
#pragma unroll
      for (int i = 0; i < 4; ++i) inv[i] = 1.0f / rs[r][i];
#pragma unroll
      for (int nc = 0; nc < 8; ++nc)
#pragma unroll
        for (int i = 0; i < 4; ++i)
          Yp[(size_t)(r * 16 + kgrp * 4 + i) * (NHEAD * DHEAD) + nc * 16 + row16] =
              f2b(y[r][nc][i] * inv[i]);
    }
  };

  runSeg(31 - qpj);   // long segment first
  runSeg(qpj);        // complementary short segment: total = 68 tiles, all blocks
}

// ---------------- output projection: 4 waves/block ----------------
__global__ __launch_bounds__(256) void k_oproj(const u16* __restrict__ Yb,
                                               const u16* __restrict__ WoB,
                                               float* __restrict__ out) {
  int wid = threadIdx.x >> 6;
  int lane = threadIdx.x & 63;
  int mb = (blockIdx.x * 4 + wid) * 32 + blockIdx.y * 16;
  int nb = blockIdx.z * 64;
  int row16 = lane & 15, kgrp = lane >> 4;
  f32x4 acc[4];
#pragma unroll
  for (int nc = 0; nc < 4; ++nc) acc[nc] = zero4();
#pragma unroll 4
  for (int kc = 0; kc < 32; ++kc) {
    bf16x8 a0 = *(const bf16x8*)(Yb + (size_t)(mb + row16) * 1024 + kc * 32 + kgrp * 8);
#pragma unroll
    for (int nc = 0; nc < 4; ++nc) {
      bf16x8 bw =
          *(const bf16x8*)(WoB + (size_t)(nb + nc * 16 + row16) * 1024 + kc * 32 + kgrp * 8);
      acc[nc] = mfma16(a0, bw, acc[nc]);
    }
  }
#pragma unroll
  for (int nc = 0; nc < 4; ++nc)
#pragma unroll
    for (int i = 0; i < 4; ++i)
      out[(size_t)(mb + kgrp * 4 + i) * DHEAD + nb + nc * 16 + row16] = acc[nc][i];
}

extern "C" void kernel_launch(void* const* d_in, const int* in_sizes, int n_in,
                              void* d_out, int out_size, void* d_ws, size_t ws_size,
                              hipStream_t stream) {
  const float* x = (const float*)d_in[0];
  const float* Wq = (const float*)d_in[1];
  const float* Wk = (const float*)d_in[2];
  const float* Wo = (const float*)d_in[3];
  float* out = (float*)d_out;

  char* ws = (char*)d_ws;
  size_t off = 0;
  auto alloc = [&](size_t bytes) -> void* {
    void* p = ws + off;
    off += (bytes + 255) & ~(size_t)255;
    return p;
  };
  const size_t nx = (size_t)NBATCH * S_LEN * DHEAD;
  const size_t nqk = (size_t)NBATCH * NHEAD * S_LEN * DHEAD;
  u16* xb = (u16*)alloc(nx * 2);
  u16* xT = (u16*)alloc(nx * 2);
  u16* Wqt = (u16*)alloc((size_t)NHEAD * DHEAD * DHEAD * 2);
  u16* Wkt = (u16*)alloc((size_t)NHEAD * DHEAD * DHEAD * 2);
  u16* WoB = (u16*)alloc((size_t)DHEAD * NHEAD * DHEAD * 2);
  u16* Qb = (u16*)alloc(nqk * 2);
  u16* Kb = (u16*)alloc(nqk * 2);
  u16* Yb = (u16*)alloc(nqk * 2);
  (void)ws_size;

  k_conv_x<<<dim3(nx / 256), dim3(256), 0, stream>>>(x, xb, xT);
  k_conv_w<<<dim3(131072 / 256), dim3(256), 0, stream>>>(Wq, Wk, Wo, Wqt, Wkt, WoB);
  k_proj<<<dim3(S_LEN / 32 / 4, NHEAD, 2 * NBATCH), dim3(256), 0, stream>>>(xb, Wqt, Wkt, Qb, Kb);
  k_attn<<<dim3(256), dim3(256), 0, stream>>>(Qb, Kb, xT, Yb);
  k_oproj<<<dim3((NBATCH * S_LEN) / 32 / 4, 2, 2), dim3(256), 0, stream>>>(Yb, WoB, out);
}

// Round 12
// 193.921 us; speedup vs baseline: 1.1482x; 1.1482x over previous
//
#include <hip/hip_runtime.h>
#include <hip/hip_bf16.h>

typedef unsigned short u16;
typedef unsigned int u32;
typedef __attribute__((ext_vector_type(8))) short bf16x8;
typedef __attribute__((ext_vector_type(4))) float f32x4;

#define S_LEN 4096
#define DHEAD 128
#define NHEAD 8
#define NBATCH 2

__device__ __forceinline__ u16 f2b(float f) {
  __hip_bfloat16 h = __float2bfloat16(f);
  return *(u16*)&h;
}

__device__ __forceinline__ f32x4 mfma16(bf16x8 a, bf16x8 b, f32x4 c) {
  return __builtin_amdgcn_mfma_f32_16x16x32_bf16(a, b, c, 0, 0, 0);
}

__device__ __forceinline__ f32x4 zero4() { f32x4 z = {0.f, 0.f, 0.f, 0.f}; return z; }

// async global->LDS, 16B per lane; LDS dest = wave-uniform base + lane*16
__device__ __forceinline__ void gll16(const u16* g, u16* l) {
  __builtin_amdgcn_global_load_lds(
      (const __attribute__((address_space(1))) u32*)g,
      (__attribute__((address_space(3))) u32*)l, 16, 0, 0);
}

// ---------------- converts ----------------
__global__ void k_conv_x(const float* __restrict__ x, u16* __restrict__ xb,
                         u16* __restrict__ xT) {
  int idx = blockIdx.x * blockDim.x + threadIdx.x;
  float v = x[idx];
  u16 bv = f2b(v);
  xb[idx] = bv;
  int d = idx & 127;
  int bs = idx >> 7;
  int b = bs >> 12;
  int s = bs & 4095;
  xT[((size_t)b * DHEAD + d) * S_LEN + s] = bv;
}

__global__ void k_conv_w(const float* __restrict__ Wq, const float* __restrict__ Wk,
                         const float* __restrict__ Wo, u16* __restrict__ Wqt,
                         u16* __restrict__ Wkt, u16* __restrict__ WoB) {
  int idx = blockIdx.x * blockDim.x + threadIdx.x;
  int h = idx >> 14;
  int d = (idx >> 7) & 127;
  int e = idx & 127;
  int t = (h << 14) + (e << 7) + d;
  Wqt[t] = f2b(Wq[idx]);
  Wkt[t] = f2b(Wk[idx]);
  WoB[idx] = f2b(Wo[idx]);
}

// ---------------- Q/K projection: 4 waves/block ----------------
__global__ __launch_bounds__(256) void k_proj(const u16* __restrict__ xb,
                                              const u16* __restrict__ Wqt,
                                              const u16* __restrict__ Wkt,
                                              u16* __restrict__ Qb, u16* __restrict__ Kb) {
  int wid = threadIdx.x >> 6;
  int lane = threadIdx.x & 63;
  int qt = blockIdx.x * 4 + wid;
  int h = blockIdx.y, z = blockIdx.z;
  int b = z >> 1, w = z & 1;
  int row16 = lane & 15, kgrp = lane >> 4;
  int sb = qt * 32;
  const u16* xp = xb + ((size_t)b * S_LEN + sb) * DHEAD;
  bf16x8 a[2][4];
#pragma unroll
  for (int r = 0; r < 2; ++r)
#pragma unroll
    for (int kc = 0; kc < 4; ++kc)
      a[r][kc] = *(const bf16x8*)(xp + (r * 16 + row16) * DHEAD + kc * 32 + kgrp * 8);

  const u16* Wt = (w == 0 ? Wqt : Wkt) + (size_t)h * DHEAD * DHEAD;
  u16* Out = (w == 0 ? Qb : Kb) + ((size_t)(b * NHEAD + h) * S_LEN + sb) * DHEAD;
  f32x4 acc[2][8];
#pragma unroll
  for (int r = 0; r < 2; ++r)
#pragma unroll
    for (int nc = 0; nc < 8; ++nc) acc[r][nc] = zero4();
#pragma unroll
  for (int kc = 0; kc < 4; ++kc)
#pragma unroll
    for (int nc = 0; nc < 8; ++nc) {
      bf16x8 bw = *(const bf16x8*)(Wt + (nc * 16 + row16) * DHEAD + kc * 32 + kgrp * 8);
      acc[0][nc] = mfma16(a[0][kc], bw, acc[0][nc]);
      acc[1][nc] = mfma16(a[1][kc], bw, acc[1][nc]);
    }
#pragma unroll
  for (int r = 0; r < 2; ++r)
#pragma unroll
    for (int nc = 0; nc < 8; ++nc)
#pragma unroll
      for (int i = 0; i < 4; ++i)
        Out[(size_t)(r * 16 + kgrp * 4 + i) * DHEAD + nc * 16 + row16] =
            f2b(acc[r][nc][i]);
}

// ---------------- causal flash attention: 8 waves/block, balanced pairs ------
// Block = (b,h, qblk-pair {j,31-j}) -> exactly 68 key-tiles; 256 blocks, flat.
// 8 waves x 16 q-rows (512 threads) -> 2 waves/SIMD: QK-MFMA of one wave
// overlaps softmax-VALU of its SIMD-mate (the r11 chain was 1 wave/SIMD).
__global__ __launch_bounds__(512) void k_attn(const u16* __restrict__ Qb,
                                              const u16* __restrict__ Kb,
                                              const u16* __restrict__ xT,
                                              u16* __restrict__ Yb) {
  int p = blockIdx.x;                      // 0..255
  int xcd = p & 7;
  int j2 = p >> 3;                         // 0..31
  int bh = xcd + (j2 >= 16 ? 8 : 0);       // 0..15 (same (b,h) per XCD)
  int qpj = j2 & 15;
  int b = bh >> 3, h = bh & 7;

  int tid = threadIdx.x;
  int wid = tid >> 6;                      // 0..7
  int lane = tid & 63;
  int row16 = lane & 15, kgrp = lane >> 4;

  const u16* Kp = Kb + (size_t)(b * NHEAD + h) * S_LEN * DHEAD;
  const u16* Vt = xT + (size_t)b * DHEAD * S_LEN;

  // fragment-linear: frag f at [f*512 .. f*512+512) u16
  __shared__ __align__(16) u16 Klds[2][8192];       // 32 KB
  __shared__ __align__(16) u16 Vlds[2][8192];       // 32 KB
  __shared__ __align__(16) u16 plds[8][16][40];     // 10 KB (per-wave P, 16 rows)

  // stage one 64-key tile: 16 K-frags + 16 V-frags, 2 gll each per wave
  auto issue = [&](int k0, int buf) {
#pragma unroll
    for (int fi = 0; fi < 2; ++fi) {
      int f = wid * 2 + fi;
      int kk = (f >> 3) & 1, nk = (f >> 2) & 1, kc = f & 3;
      const u16* src =
          Kp + (size_t)(k0 + kk * 32 + nk * 16 + row16) * DHEAD + kc * 32 + kgrp * 8;
      gll16(src, &Klds[buf][f * 512]);
    }
#pragma unroll
    for (int gi = 0; gi < 2; ++gi) {
      int g = wid * 2 + gi;
      int kk = g >> 3, nc = g & 7;
      const u16* src = Vt + (size_t)(nc * 16 + row16) * S_LEN + k0 + kk * 32 + kgrp * 8;
      gll16(src, &Vlds[buf][g * 512]);
    }
  };

  const float c2 = 0.12754274816295166f;    // (1/sqrt(128)) * log2(e)
  const float clip2 = 14.426950408889634f;  // 10 * log2(e)

  auto runSeg = [&](int qblk) {
    int qb0 = qblk * 128;
    int qw = qb0 + wid * 16;               // this wave's 16 q-rows
    const u16* Qp = Qb + ((size_t)(b * NHEAD + h) * S_LEN + qw) * DHEAD;

    bf16x8 aq[4];
#pragma unroll
    for (int kc = 0; kc < 4; ++kc)
      aq[kc] = *(const bf16x8*)(Qp + row16 * DHEAD + kc * 32 + kgrp * 8);

    f32x4 y[8];
#pragma unroll
    for (int nc = 0; nc < 8; ++nc) y[nc] = zero4();
    f32x4 rs = zero4();

    auto subtile = [&](int buf, int k0, int kk) {
      bf16x8 kf[8];
#pragma unroll
      for (int nk = 0; nk < 2; ++nk)
#pragma unroll
        for (int kc = 0; kc < 4; ++kc)
          kf[nk * 4 + kc] =
              *(const bf16x8*)&Klds[buf][((kk * 8 + nk * 4 + kc) * 64 + lane) * 8];
      f32x4 sc[2];
      sc[0] = zero4();
      sc[1] = zero4();
#pragma unroll
      for (int nk = 0; nk < 2; ++nk)
#pragma unroll
        for (int kcc = 0; kcc < 4; ++kcc)
          sc[nk] = mfma16(aq[kcc], kf[nk * 4 + kcc], sc[nk]);
#pragma unroll
      for (int nk = 0; nk < 2; ++nk) {
        int key = k0 + kk * 32 + nk * 16 + row16;
#pragma unroll
        for (int i = 0; i < 4; ++i) {
          float v = sc[nk][i] * c2;
          v = fminf(fmaxf(v, -clip2), clip2);
          float pcur = __builtin_amdgcn_exp2f(v);
          int qrow = qw + kgrp * 4 + i;
          pcur = (key > qrow) ? 0.0f : pcur;   // branchless causal mask
          rs[i] += pcur;
          plds[wid][kgrp * 4 + i][nk * 16 + row16] = f2b(pcur);
        }
      }
      bf16x8 ap = *(const bf16x8*)&plds[wid][row16][kgrp * 8];
#pragma unroll
      for (int nc = 0; nc < 8; ++nc) {
        bf16x8 vf = *(const bf16x8*)&Vlds[buf][((kk * 8 + nc) * 64 + lane) * 8];
        y[nc] = mfma16(ap, vf, y[nc]);
      }
    };

    int NT = 2 * qblk + 2;   // 64-key tiles covering keys 0..qb0+127
    issue(0, 0);
    __syncthreads();
    for (int t = 0; t < NT; ++t) {
      int k0 = t * 64;
      int cur = t & 1;
      if (t + 1 < NT) issue(k0 + 64, cur ^ 1);  // prefetch under full tile compute
      subtile(cur, k0, 0);
      subtile(cur, k0, 1);
      __syncthreads();  // drains vmcnt (prefetch landed) + LDS reads done
    }

    // reduce rs over the 16 row16 lanes of each kgrp group
#pragma unroll
    for (int i = 0; i < 4; ++i) {
      float v = rs[i];
      v += __shfl_xor(v, 1, 64);
      v += __shfl_xor(v, 2, 64);
      v += __shfl_xor(v, 4, 64);
      v += __shfl_xor(v, 8, 64);
      rs[i] = v;
    }

    u16* Yp = Yb + ((size_t)b * S_LEN + qw) * (NHEAD * DHEAD) + h * DHEAD;
    float inv[4];
#pragma unroll
    for (int i = 0; i < 4; ++i) inv[i] = 1.0f / rs[i];
#pragma unroll
    for (int nc = 0; nc < 8; ++nc)
#pragma unroll
      for (int i = 0; i < 4; ++i)
        Yp[(size_t)(kgrp * 4 + i) * (NHEAD * DHEAD) + nc * 16 + row16] =
            f2b(y[nc][i] * inv[i]);
  };

  runSeg(31 - qpj);   // long segment first
  runSeg(qpj);        // complementary short segment: 68 tiles for every block
}

// ---------------- output projection: 4 waves/block ----------------
__global__ __launch_bounds__(256) void k_oproj(const u16* __restrict__ Yb,
                                               const u16* __restrict__ WoB,
                                               float* __restrict__ out) {
  int wid = threadIdx.x >> 6;
  int lane = threadIdx.x & 63;
  int mb = (blockIdx.x * 4 + wid) * 32 + blockIdx.y * 16;
  int nb = blockIdx.z * 64;
  int row16 = lane & 15, kgrp = lane >> 4;
  f32x4 acc[4];
#pragma unroll
  for (int nc = 0; nc < 4; ++nc) acc[nc] = zero4();
#pragma unroll 4
  for (int kc = 0; kc < 32; ++kc) {
    bf16x8 a0 = *(const bf16x8*)(Yb + (size_t)(mb + row16) * 1024 + kc * 32 + kgrp * 8);
#pragma unroll
    for (int nc = 0; nc < 4; ++nc) {
      bf16x8 bw =
          *(const bf16x8*)(WoB + (size_t)(nb + nc * 16 + row16) * 1024 + kc * 32 + kgrp * 8);
      acc[nc] = mfma16(a0, bw, acc[nc]);
    }
  }
#pragma unroll
  for (int nc = 0; nc < 4; ++nc)
#pragma unroll
    for (int i = 0; i < 4; ++i)
      out[(size_t)(mb + kgrp * 4 + i) * DHEAD + nb + nc * 16 + row16] = acc[nc][i];
}

extern "C" void kernel_launch(void* const* d_in, const int* in_sizes, int n_in,
                              void* d_out, int out_size, void* d_ws, size_t ws_size,
                              hipStream_t stream) {
  const float* x = (const float*)d_in[0];
  const float* Wq = (const float*)d_in[1];
  const float* Wk = (const float*)d_in[2];
  const float* Wo = (const float*)d_in[3];
  float* out = (float*)d_out;

  char* ws = (char*)d_ws;
  size_t off = 0;
  auto alloc = [&](size_t bytes) -> void* {
    void* p = ws + off;
    off += (bytes + 255) & ~(size_t)255;
    return p;
  };
  const size_t nx = (size_t)NBATCH * S_LEN * DHEAD;
  const size_t nqk = (size_t)NBATCH * NHEAD * S_LEN * DHEAD;
  u16* xb = (u16*)alloc(nx * 2);
  u16* xT = (u16*)alloc(nx * 2);
  u16* Wqt = (u16*)alloc((size_t)NHEAD * DHEAD * DHEAD * 2);
  u16* Wkt = (u16*)alloc((size_t)NHEAD * DHEAD * DHEAD * 2);
  u16* WoB = (u16*)alloc((size_t)DHEAD * NHEAD * DHEAD * 2);
  u16* Qb = (u16*)alloc(nqk * 2);
  u16* Kb = (u16*)alloc(nqk * 2);
  u16* Yb = (u16*)alloc(nqk * 2);
  (void)ws_size;

  k_conv_x<<<dim3(nx / 256), dim3(256), 0, stream>>>(x, xb, xT);
  k_conv_w<<<dim3(131072 / 256), dim3(256), 0, stream>>>(Wq, Wk, Wo, Wqt, Wkt, WoB);
  k_proj<<<dim3(S_LEN / 32 / 4, NHEAD, 2 * NBATCH), dim3(256), 0, stream>>>(xb, Wqt, Wkt, Qb, Kb);
  k_attn<<<dim3(256), dim3(512), 0, stream>>>(Qb, Kb, xT, Yb);
  k_oproj<<<dim3((NBATCH * S_LEN) / 32 / 4, 2, 2), dim3(256), 0, stream>>>(Yb, WoB, out);
}

// Round 13
// 184.538 us; speedup vs baseline: 1.2066x; 1.0508x over previous
//
#include <hip/hip_runtime.h>
#include <hip/hip_bf16.h>

typedef unsigned short u16;
typedef unsigned int u32;
typedef __attribute__((ext_vector_type(8))) short bf16x8;
typedef __attribute__((ext_vector_type(4))) float f32x4;

#define S_LEN 4096
#define DHEAD 128
#define NHEAD 8
#define NBATCH 2

__device__ __forceinline__ u16 f2b(float f) {
  __hip_bfloat16 h = __float2bfloat16(f);
  return *(u16*)&h;
}

__device__ __forceinline__ f32x4 mfma16(bf16x8 a, bf16x8 b, f32x4 c) {
  return __builtin_amdgcn_mfma_f32_16x16x32_bf16(a, b, c, 0, 0, 0);
}

__device__ __forceinline__ f32x4 zero4() { f32x4 z = {0.f, 0.f, 0.f, 0.f}; return z; }

// async global->LDS, 16B per lane; LDS dest = wave-uniform base + lane*16
__device__ __forceinline__ void gll16(const u16* g, u16* l) {
  __builtin_amdgcn_global_load_lds(
      (const __attribute__((address_space(1))) u32*)g,
      (__attribute__((address_space(3))) u32*)l, 16, 0, 0);
}

// ---------------- converts ----------------
__global__ void k_conv_x(const float* __restrict__ x, u16* __restrict__ xb,
                         u16* __restrict__ xT) {
  int idx = blockIdx.x * blockDim.x + threadIdx.x;
  float v = x[idx];
  u16 bv = f2b(v);
  xb[idx] = bv;
  int d = idx & 127;
  int bs = idx >> 7;
  int b = bs >> 12;
  int s = bs & 4095;
  xT[((size_t)b * DHEAD + d) * S_LEN + s] = bv;
}

__global__ void k_conv_w(const float* __restrict__ Wq, const float* __restrict__ Wk,
                         const float* __restrict__ Wo, u16* __restrict__ Wqt,
                         u16* __restrict__ Wkt, u16* __restrict__ WoB) {
  int idx = blockIdx.x * blockDim.x + threadIdx.x;
  int h = idx >> 14;
  int d = (idx >> 7) & 127;
  int e = idx & 127;
  int t = (h << 14) + (e << 7) + d;
  Wqt[t] = f2b(Wq[idx]);
  Wkt[t] = f2b(Wk[idx]);
  WoB[idx] = f2b(Wo[idx]);
}

// ---------------- Q/K projection: 4 waves/block ----------------
__global__ __launch_bounds__(256) void k_proj(const u16* __restrict__ xb,
                                              const u16* __restrict__ Wqt,
                                              const u16* __restrict__ Wkt,
                                              u16* __restrict__ Qb, u16* __restrict__ Kb) {
  int wid = threadIdx.x >> 6;
  int lane = threadIdx.x & 63;
  int qt = blockIdx.x * 4 + wid;
  int h = blockIdx.y, z = blockIdx.z;
  int b = z >> 1, w = z & 1;
  int row16 = lane & 15, kgrp = lane >> 4;
  int sb = qt * 32;
  const u16* xp = xb + ((size_t)b * S_LEN + sb) * DHEAD;
  bf16x8 a[2][4];
#pragma unroll
  for (int r = 0; r < 2; ++r)
#pragma unroll
    for (int kc = 0; kc < 4; ++kc)
      a[r][kc] = *(const bf16x8*)(xp + (r * 16 + row16) * DHEAD + kc * 32 + kgrp * 8);

  const u16* Wt = (w == 0 ? Wqt : Wkt) + (size_t)h * DHEAD * DHEAD;
  u16* Out = (w == 0 ? Qb : Kb) + ((size_t)(b * NHEAD + h) * S_LEN + sb) * DHEAD;
  f32x4 acc[2][8];
#pragma unroll
  for (int r = 0; r < 2; ++r)
#pragma unroll
    for (int nc = 0; nc < 8; ++nc) acc[r][nc] = zero4();
#pragma unroll
  for (int kc = 0; kc < 4; ++kc)
#pragma unroll
    for (int nc = 0; nc < 8; ++nc) {
      bf16x8 bw = *(const bf16x8*)(Wt + (nc * 16 + row16) * DHEAD + kc * 32 + kgrp * 8);
      acc[0][nc] = mfma16(a[0][kc], bw, acc[0][nc]);
      acc[1][nc] = mfma16(a[1][kc], bw, acc[1][nc]);
    }
#pragma unroll
  for (int r = 0; r < 2; ++r)
#pragma unroll
    for (int nc = 0; nc < 8; ++nc)
#pragma unroll
      for (int i = 0; i < 4; ++i)
        Out[(size_t)(r * 16 + kgrp * 4 + i) * DHEAD + nc * 16 + row16] =
            f2b(acc[r][nc][i]);
}

// ---------------- causal flash attention: 8 waves = 4q x 2key-halves ---------
// Block = (b,h, qblk-pair {j,31-j}) -> exactly 68 key-tiles; 256 blocks, flat.
// Wave (qr,kh): 32 q-rows x its 32-key half -> K/V LDS reads HALVED vs r12
// (17 b128/wave/tile) while keeping 2 waves/SIMD. Key-half partials combined
// once per segment through the then-dead K/V LDS.
__global__ __launch_bounds__(512) void k_attn(const u16* __restrict__ Qb,
                                              const u16* __restrict__ Kb,
                                              const u16* __restrict__ xT,
                                              u16* __restrict__ Yb) {
  int p = blockIdx.x;                      // 0..255
  int xcd = p & 7;
  int j2 = p >> 3;                         // 0..31
  int bh = xcd + (j2 >= 16 ? 8 : 0);       // 0..15 (same (b,h) per XCD)
  int qpj = j2 & 15;
  int b = bh >> 3, h = bh & 7;

  int tid = threadIdx.x;
  int wid = tid >> 6;                      // 0..7
  int lane = tid & 63;
  int qr = wid >> 1;                       // 0..3 q-subgroup (32 rows)
  int kh = wid & 1;                        // 0..1 key half (32 keys)
  int row16 = lane & 15, kgrp = lane >> 4;

  const u16* Kp = Kb + (size_t)(b * NHEAD + h) * S_LEN * DHEAD;
  const u16* Vt = xT + (size_t)b * DHEAD * S_LEN;

  // fragment-linear: frag f at [f*512 .. f*512+512) u16
  __shared__ __align__(16) u16 Klds[2][8192];       // 32 KB
  __shared__ __align__(16) u16 Vlds[2][8192];       // 32 KB
  __shared__ __align__(16) u16 plds[8][32][40];     // 20 KB (per-wave P)

  // stage one 64-key tile: 16 K-frags + 16 V-frags, 2+2 gll per wave
  auto issue = [&](int k0, int buf) {
#pragma unroll
    for (int fi = 0; fi < 2; ++fi) {
      int f = wid * 2 + fi;
      int kk = (f >> 3) & 1, nk = (f >> 2) & 1, kc = f & 3;
      const u16* src =
          Kp + (size_t)(k0 + kk * 32 + nk * 16 + row16) * DHEAD + kc * 32 + kgrp * 8;
      gll16(src, &Klds[buf][f * 512]);
    }
#pragma unroll
    for (int gi = 0; gi < 2; ++gi) {
      int g = wid * 2 + gi;
      int kk = g >> 3, nc = g & 7;
      const u16* src = Vt + (size_t)(nc * 16 + row16) * S_LEN + k0 + kk * 32 + kgrp * 8;
      gll16(src, &Vlds[buf][g * 512]);
    }
  };

  const float c2 = 0.12754274816295166f;    // (1/sqrt(128)) * log2(e)
  const float clip2 = 14.426950408889634f;  // 10 * log2(e)

  auto runSeg = [&](int qblk) {
    int qb0 = qblk * 128;
    int qw = qb0 + qr * 32;                // this wave's 32 q-rows
    const u16* Qp = Qb + ((size_t)(b * NHEAD + h) * S_LEN + qw) * DHEAD;

    bf16x8 aq[2][4];
#pragma unroll
    for (int r = 0; r < 2; ++r)
#pragma unroll
      for (int kc = 0; kc < 4; ++kc)
        aq[r][kc] = *(const bf16x8*)(Qp + (r * 16 + row16) * DHEAD + kc * 32 + kgrp * 8);

    f32x4 y[2][8];
#pragma unroll
    for (int r = 0; r < 2; ++r)
#pragma unroll
      for (int nc = 0; nc < 8; ++nc) y[r][nc] = zero4();
    f32x4 rs[2];
    rs[0] = zero4();
    rs[1] = zero4();

    // one pass per tile: this wave's 32-key half only
    auto tilecomp = [&](int buf, int k0) {
      bf16x8 kf[8];
#pragma unroll
      for (int nk = 0; nk < 2; ++nk)
#pragma unroll
        for (int kc = 0; kc < 4; ++kc)
          kf[nk * 4 + kc] =
              *(const bf16x8*)&Klds[buf][((kh * 8 + nk * 4 + kc) * 64 + lane) * 8];
      f32x4 sc[2][2];
      sc[0][0] = zero4(); sc[0][1] = zero4(); sc[1][0] = zero4(); sc[1][1] = zero4();
#pragma unroll
      for (int nk = 0; nk < 2; ++nk)
#pragma unroll
        for (int kcc = 0; kcc < 4; ++kcc) {
          sc[0][nk] = mfma16(aq[0][kcc], kf[nk * 4 + kcc], sc[0][nk]);
          sc[1][nk] = mfma16(aq[1][kcc], kf[nk * 4 + kcc], sc[1][nk]);
        }
#pragma unroll
      for (int r = 0; r < 2; ++r)
#pragma unroll
        for (int nk = 0; nk < 2; ++nk) {
          int key = k0 + kh * 32 + nk * 16 + row16;
#pragma unroll
          for (int i = 0; i < 4; ++i) {
            float v = sc[r][nk][i] * c2;
            v = fminf(fmaxf(v, -clip2), clip2);
            float pcur = __builtin_amdgcn_exp2f(v);
            int qrow = qw + r * 16 + kgrp * 4 + i;
            pcur = (key > qrow) ? 0.0f : pcur;   // branchless causal mask
            rs[r][i] += pcur;
            plds[wid][r * 16 + kgrp * 4 + i][nk * 16 + row16] = f2b(pcur);
          }
        }
      bf16x8 ap0 = *(const bf16x8*)&plds[wid][row16][kgrp * 8];
      bf16x8 ap1 = *(const bf16x8*)&plds[wid][16 + row16][kgrp * 8];
#pragma unroll
      for (int nc = 0; nc < 8; ++nc) {
        bf16x8 vf = *(const bf16x8*)&Vlds[buf][((kh * 8 + nc) * 64 + lane) * 8];
        y[0][nc] = mfma16(ap0, vf, y[0][nc]);
        y[1][nc] = mfma16(ap1, vf, y[1][nc]);
      }
    };

    int NT = 2 * qblk + 2;   // 64-key tiles covering keys 0..qb0+127
    issue(0, 0);
    __syncthreads();
    for (int t = 0; t < NT; ++t) {
      int k0 = t * 64;
      int cur = t & 1;
      if (t + 1 < NT) issue(k0 + 64, cur ^ 1);  // prefetch under tile compute
      tilecomp(cur, k0);
      __syncthreads();  // drains vmcnt (prefetch landed) + LDS reads done
    }

    // reduce rs over the 16 row16 lanes of each kgrp group
#pragma unroll
    for (int r = 0; r < 2; ++r)
#pragma unroll
      for (int i = 0; i < 4; ++i) {
        float v = rs[r][i];
        v += __shfl_xor(v, 1, 64);
        v += __shfl_xor(v, 2, 64);
        v += __shfl_xor(v, 4, 64);
        v += __shfl_xor(v, 8, 64);
        rs[r][i] = v;
      }

    // combine key halves through the (now dead) K/V LDS
    float* rscr = (float*)&plds[0][0][0];            // 128 floats used
    float* scr = (qr < 2) ? ((float*)&Klds[0][0] + qr * 4096)
                          : ((float*)&Vlds[0][0] + (qr - 2) * 4096);
    if (kh == 1) {
#pragma unroll
      for (int r = 0; r < 2; ++r)
#pragma unroll
        for (int nc = 0; nc < 8; ++nc)
          *(f32x4*)&scr[((r * 8 + nc) * 64 + lane) * 4] = y[r][nc];
      if (row16 == 0) {
#pragma unroll
        for (int r = 0; r < 2; ++r)
#pragma unroll
          for (int i = 0; i < 4; ++i)
            rscr[qr * 32 + r * 16 + kgrp * 4 + i] = rs[r][i];
      }
    }
    __syncthreads();
    if (kh == 0) {
#pragma unroll
      for (int r = 0; r < 2; ++r)
#pragma unroll
        for (int nc = 0; nc < 8; ++nc)
          y[r][nc] += *(const f32x4*)&scr[((r * 8 + nc) * 64 + lane) * 4];
#pragma unroll
      for (int r = 0; r < 2; ++r)
#pragma unroll
        for (int i = 0; i < 4; ++i)
          rs[r][i] += rscr[qr * 32 + r * 16 + kgrp * 4 + i];

      u16* Yp = Yb + ((size_t)b * S_LEN + qw) * (NHEAD * DHEAD) + h * DHEAD;
#pragma unroll
      for (int r = 0; r < 2; ++r) {
        float inv[4];
#pragma unroll
        for (int i = 0; i < 4; ++i) inv[i] = 1.0f / rs[r][i];
#pragma unroll
        for (int nc = 0; nc < 8; ++nc)
#pragma unroll
          for (int i = 0; i < 4; ++i)
            Yp[(size_t)(r * 16 + kgrp * 4 + i) * (NHEAD * DHEAD) + nc * 16 + row16] =
                f2b(y[r][nc][i] * inv[i]);
      }
    }
    __syncthreads();  // scratch reads done before next segment stages over it
  };

  runSeg(31 - qpj);   // long segment first
  runSeg(qpj);        // complementary short: 68 tiles for every block, flat
}

// ---------------- output projection: 4 waves/block ----------------
__global__ __launch_bounds__(256) void k_oproj(const u16* __restrict__ Yb,
                                               const u16* __restrict__ WoB,
                                               float* __restrict__ out) {
  int wid = threadIdx.x >> 6;
  int lane = threadIdx.x & 63;
  int mb = (blockIdx.x * 4 + wid) * 32 + blockIdx.y * 16;
  int nb = blockIdx.z * 64;
  int row16 = lane & 15, kgrp = lane >> 4;
  f32x4 acc[4];
#pragma unroll
  for (int nc = 0; nc < 4; ++nc) acc[nc] = zero4();
#pragma unroll 4
  for (int kc = 0; kc < 32; ++kc) {
    bf16x8 a0 = *(const bf16x8*)(Yb + (size_t)(mb + row16) * 1024 + kc * 32 + kgrp * 8);
#pragma unroll
    for (int nc = 0; nc < 4; ++nc) {
      bf16x8 bw =
          *(const bf16x8*)(WoB + (size_t)(nb + nc * 16 + row16) * 1024 + kc * 32 + kgrp * 8);
      acc[nc] = mfma16(a0, bw, acc[nc]);
    }
  }
#pragma unroll
  for (int nc = 0; nc < 4; ++nc)
#pragma unroll
    for (int i = 0; i < 4; ++i)
      out[(size_t)(mb + kgrp * 4 + i) * DHEAD + nb + nc * 16 + row16] = acc[nc][i];
}

extern "C" void kernel_launch(void* const* d_in, const int* in_sizes, int n_in,
                              void* d_out, int out_size, void* d_ws, size_t ws_size,
                              hipStream_t stream) {
  const float* x = (const float*)d_in[0];
  const float* Wq = (const float*)d_in[1];
  const float* Wk = (const float*)d_in[2];
  const float* Wo = (const float*)d_in[3];
  float* out = (float*)d_out;

  char* ws = (char*)d_ws;
  size_t off = 0;
  auto alloc = [&](size_t bytes) -> void* {
    void* p = ws + off;
    off += (bytes + 255) & ~(size_t)255;
    return p;
  };
  const size_t nx = (size_t)NBATCH * S_LEN * DHEAD;
  const size_t nqk = (size_t)NBATCH * NHEAD * S_LEN * DHEAD;
  u16* xb = (u16*)alloc(nx * 2);
  u16* xT = (u16*)alloc(nx * 2);
  u16* Wqt = (u16*)alloc((size_t)NHEAD * DHEAD * DHEAD * 2);
  u16* Wkt = (u16*)alloc((size_t)NHEAD * DHEAD * DHEAD * 2);
  u16* WoB = (u16*)alloc((size_t)DHEAD * NHEAD * DHEAD * 2);
  u16* Qb = (u16*)alloc(nqk * 2);
  u16* Kb = (u16*)alloc(nqk * 2);
  u16* Yb = (u16*)alloc(nqk * 2);
  (void)ws_size;

  k_conv_x<<<dim3(nx / 256), dim3(256), 0, stream>>>(x, xb, xT);
  k_conv_w<<<dim3(131072 / 256), dim3(256), 0, stream>>>(Wq, Wk, Wo, Wqt, Wkt, WoB);
  k_proj<<<dim3(S_LEN / 32 / 4, NHEAD, 2 * NBATCH), dim3(256), 0, stream>>>(xb, Wqt, Wkt, Qb, Kb);
  k_attn<<<dim3(256), dim3(512), 0, stream>>>(Qb, Kb, xT, Yb);
  k_oproj<<<dim3((NBATCH * S_LEN) / 32 / 4, 2, 2), dim3(256), 0, stream>>>(Yb, WoB, out);
}